// Round 12
// baseline (197.777 us; speedup 1.0000x reference)
//
#include <hip/hip_runtime.h>
#include <hip/hip_bf16.h>
#include <hip/hip_fp16.h>

#define IN_DIM 128
#define C_DIM 64
#define SH    9            // dsts per bucket = 512
#define DP    512
#define CAP   10240        // records per bucket region (avg 8192)
#define NBKT2 256          // padded bucket-array size in K1 (196 actual)
#define DPH   256          // dsts per half-bucket
#define CAPH  6144         // LDS records per half-bucket (mean 4096, +32 sigma)

typedef __attribute__((ext_vector_type(8))) short bf16x8;
typedef __attribute__((ext_vector_type(4))) float f32x4;

__device__ __forceinline__ short f2b(float f) {
    unsigned u = __float_as_uint(f);
    unsigned r = (u + 0x7FFFu + ((u >> 16) & 1u)) >> 16;   // RNE to bf16
    return (short)r;
}

// record: x = src; y = (d_local<<15) | beta15
__device__ __forceinline__ int2 make_rec(int s, int dl, float b) {
    unsigned b15 = (unsigned)(b * 32767.f + 0.5f) & 0x7FFFu;
    return make_int2(s, (int)(((unsigned)dl << 15) | b15));
}

// ---------------------------------------------------------------------------
// K1 fused (UNCHANGED): gemm role + LDS-binned edge staging into gbuf.
// ---------------------------------------------------------------------------
__global__ __launch_bounds__(256) void k_fused(
    const float* __restrict__ x,
    const float* __restrict__ W,
    const float* __restrict__ att_src,
    const float* __restrict__ att_dst,
    unsigned short* __restrict__ xp_bf,
    float* __restrict__ s_src,
    float* __restrict__ s_dst,
    const int* __restrict__ ei_src,
    const int* __restrict__ ei_dst,
    const float* __restrict__ beta,
    int* __restrict__ gcur,
    int2* __restrict__ gbuf,
    int n, int e, int gd, int gg, int S)
{
    __shared__ char smem[23552];

    const int bid = (int)blockIdx.x;
    const int q   = bid / S;
    const bool bin_role = (bid % S == 0) && (q < gd);
    const int chunk = bin_role ? q : (bid - min(gd, q + 1));
    const int t = threadIdx.x;

    if (bin_role) {
        int2*           stag  = (int2*)smem;                     // 2048 recs
        unsigned short* sbkt  = (unsigned short*)(smem + 16384); // 2048
        int*            bcnt  = (int*)(smem + 20480);            // 256
        int*            bpre  = (int*)(smem + 21504);            // 256
        int*            gbase = (int*)(smem + 22528);            // 256

        for (int i = t; i < NBKT2; i += 256) bcnt[i] = 0;
        __syncthreads();

        const int i0 = (chunk * 256 + t) * 8;
        int   sv[8], dv[8], bkt[8], lr[8];
        float bv[8];
        int   nk = 0;
        if (i0 + 7 < e) {
            int4   sa = *(const int4*)&ei_src[i0];
            int4   sb = *(const int4*)&ei_src[i0 + 4];
            int4   da = *(const int4*)&ei_dst[i0];
            int4   db = *(const int4*)&ei_dst[i0 + 4];
            float4 ba = *(const float4*)&beta[i0];
            float4 bb = *(const float4*)&beta[i0 + 4];
            sv[0]=sa.x; sv[1]=sa.y; sv[2]=sa.z; sv[3]=sa.w;
            sv[4]=sb.x; sv[5]=sb.y; sv[6]=sb.z; sv[7]=sb.w;
            dv[0]=da.x; dv[1]=da.y; dv[2]=da.z; dv[3]=da.w;
            dv[4]=db.x; dv[5]=db.y; dv[6]=db.z; dv[7]=db.w;
            bv[0]=ba.x; bv[1]=ba.y; bv[2]=ba.z; bv[3]=ba.w;
            bv[4]=bb.x; bv[5]=bb.y; bv[6]=bb.z; bv[7]=bb.w;
            nk = 8;
        } else {
            for (int k = 0; i0 + k < e && k < 8; ++k) {
                sv[k] = ei_src[i0 + k];
                dv[k] = ei_dst[i0 + k];
                bv[k] = beta[i0 + k];
                ++nk;
            }
        }
        for (int k = 0; k < nk; ++k) {
            bkt[k] = dv[k] >> SH;
            lr[k]  = atomicAdd(&bcnt[bkt[k]], 1);
        }
        __syncthreads();

        if (t < 64) {                        // scan 256 entries, 4/lane
            int c[4], s = 0;
            #pragma unroll
            for (int j = 0; j < 4; ++j) { c[j] = bcnt[4 * t + j]; s += c[j]; }
            int v = s;
            #pragma unroll
            for (int off = 1; off < 64; off <<= 1) {
                int u = __shfl_up(v, off, 64);
                if (t >= off) v += u;
            }
            int base = v - s;
            #pragma unroll
            for (int j = 0; j < 4; ++j) { bpre[4 * t + j] = base; base += c[j]; }
        }
        __syncthreads();

        if (t < NBKT2) {
            int c = bcnt[t];
            if (c > 0) gbase[t] = atomicAdd(&gcur[t], c);
        }
        __syncthreads();

        for (int k = 0; k < nk; ++k) {
            int slot = bpre[bkt[k]] + lr[k];
            stag[slot] = make_rec(sv[k], dv[k] & (DP - 1), bv[k]);
            sbkt[slot] = (unsigned short)bkt[k];
        }
        __syncthreads();

        const int total = bpre[NBKT2 - 1] + bcnt[NBKT2 - 1];
        for (int i = t; i < total; i += 256) {
            int bb = sbkt[i];
            int al = gbase[bb] + (i - bpre[bb]);
            if (al < CAP) gbuf[(size_t)bb * CAP + al] = stag[i];
        }
        return;
    }

    // ---- GEMM role (unchanged) ----
    short (*WT)[136] = (short(*)[136])smem;
    for (int i = t; i < IN_DIM * C_DIM; i += 256) {
        int k = i >> 6, nn = i & 63;
        WT[nn][k] = f2b(W[i]);
    }
    __syncthreads();

    const int lane = t & 63;
    const int wv   = t >> 6;
    const int base = (chunk * 4 + wv) * 16;
    if (base >= n) return;

    const int m    = lane & 15;
    const int quad = lane >> 4;
    int rowA = base + m;
    if (rowA >= n) rowA = n - 1;
    const float* xr = x + (size_t)rowA * IN_DIM + quad * 8;

    f32x4 acc[4] = {{0,0,0,0},{0,0,0,0},{0,0,0,0},{0,0,0,0}};

    #pragma unroll
    for (int ks = 0; ks < 4; ++ks) {
        float4 f0 = *(const float4*)(xr + ks * 32);
        float4 f1 = *(const float4*)(xr + ks * 32 + 4);
        bf16x8 a;
        a[0] = f2b(f0.x); a[1] = f2b(f0.y); a[2] = f2b(f0.z); a[3] = f2b(f0.w);
        a[4] = f2b(f1.x); a[5] = f2b(f1.y); a[6] = f2b(f1.z); a[7] = f2b(f1.w);
        #pragma unroll
        for (int nt = 0; nt < 4; ++nt) {
            bf16x8 bb = *(const bf16x8*)&WT[nt * 16 + m][ks * 32 + quad * 8];
            acc[nt] = __builtin_amdgcn_mfma_f32_16x16x32_bf16(a, bb, acc[nt], 0, 0, 0);
        }
    }

    float asv[4], adv[4];
    #pragma unroll
    for (int nt = 0; nt < 4; ++nt) {
        asv[nt] = att_src[nt * 16 + m];
        adv[nt] = att_dst[nt * 16 + m];
    }
    #pragma unroll
    for (int qq = 0; qq < 4; ++qq) {
        float vs = 0.f, vd = 0.f;
        #pragma unroll
        for (int nt = 0; nt < 4; ++nt) {
            vs = fmaf(acc[nt][qq], asv[nt], vs);
            vd = fmaf(acc[nt][qq], adv[nt], vd);
        }
        #pragma unroll
        for (int off = 8; off > 0; off >>= 1) {
            vs += __shfl_xor(vs, off, 64);
            vd += __shfl_xor(vd, off, 64);
        }
        int r = base + quad * 4 + qq;
        if (m == 0 && r < n) { s_src[r] = vs; s_dst[r] = vd; }
    }

    #pragma unroll
    for (int nt = 0; nt < 4; ++nt)
        #pragma unroll
        for (int qq = 0; qq < 4; ++qq) {
            int r = base + quad * 4 + qq;
            if (r < n)
                xp_bf[(size_t)r * C_DIM + nt * 16 + m] = (unsigned short)f2b(acc[nt][qq]);
        }
}

// ---------------------------------------------------------------------------
// K2 MERGED (k_sort + k_seg): one block per HALF-bucket (256 dsts).
// Pass1: count this half's records from gbuf. Scan (wave 0). Pass2: scatter
// sorted into LDS stag (gbuf re-read is L2-hot). Reduce: 8 waves x dst
// pairs, half-wave per dst; softmax g written back into the LDS record
// (same wave -> no sync), j-loop reads (src,g) via LDS broadcast --
// no gsort/gmeta round-trip, no shfl broadcasts.
// ---------------------------------------------------------------------------
__global__ __launch_bounds__(512) void k_sred(
    const int* __restrict__ gcur,
    const int2* __restrict__ gbuf,
    const unsigned short* __restrict__ xp_bf,
    const float* __restrict__ s_src,
    const float* __restrict__ s_dst,
    const float* __restrict__ lam01,
    float* __restrict__ out,
    int n)
{
    __shared__ int2 stag[CAPH];
    __shared__ int  cnt[DPH];
    __shared__ int  pre[DPH + 1];
    __shared__ int  fill[DPH];

    const int blk = (int)blockIdx.x;
    const int b   = blk >> 1;
    const int h   = blk & 1;
    const int t   = threadIdx.x;
    const int m   = min(gcur[b], CAP);
    const int2* reg = gbuf + (size_t)b * CAP;

    for (int i = t; i < DPH; i += 512) { cnt[i] = 0; fill[i] = 0; }
    __syncthreads();

    // pass 1: count kept records
    for (int i = t; i < m; i += 512) {
        int dl = (reg[i].y >> 15) & (DP - 1);
        if ((dl >> 8) == h) atomicAdd(&cnt[dl & (DPH - 1)], 1);
    }
    __syncthreads();

    // scan 256 counters (wave 0), per-dst clamp 64
    if (t < 64) {
        int c[4], s = 0;
        #pragma unroll
        for (int j = 0; j < 4; ++j) { c[j] = min(cnt[4 * t + j], 64); s += c[j]; }
        int v = s;
        #pragma unroll
        for (int off = 1; off < 64; off <<= 1) {
            int u = __shfl_up(v, off, 64);
            if (t >= off) v += u;
        }
        int base = v - s;
        #pragma unroll
        for (int j = 0; j < 4; ++j) { pre[4 * t + j] = base; base += c[j]; }
        if (t == 63) pre[DPH] = v;
    }
    __syncthreads();

    // pass 2: scatter sorted into LDS
    for (int i = t; i < m; i += 512) {
        int2 r = reg[i];
        int dl = (r.y >> 15) & (DP - 1);
        if ((dl >> 8) == h) {
            int c = dl & (DPH - 1);
            int l = atomicAdd(&fill[c], 1);
            int lim = pre[c + 1] - pre[c];
            int idx = pre[c] + l;
            if (l < lim && idx < CAPH)
                stag[idx] = make_int2(r.x, r.y & 0x7FFF);
        }
    }
    __syncthreads();

    // reduce: 8 waves, 2 dsts per wave-iteration (half-wave each)
    const int lane = t & 63;
    const int wv   = t >> 6;
    const int half = lane & 32;
    const int l31  = lane & 31;
    const float lam = lam01[0];
    const float oml = 1.f - lam;
    const float ib  = 1.f / 32767.f;
    const unsigned* xp32 = (const unsigned*)xp_bf;

    for (int lp = wv; lp < DPH / 2; lp += 8) {
        const int dl0 = 2 * lp;
        const int T0a = min(pre[dl0 + 1] - pre[dl0], CAPH - pre[dl0]);
        const int T1a = min(pre[dl0 + 2] - pre[dl0 + 1], CAPH - pre[dl0 + 1]);
        const int T0 = max(T0a, 0), T1 = max(T1a, 0);
        const int Tm = max(T0, T1);
        if (Tm == 0) {   // still must zero outputs for these dsts
            const int d = (b << SH) + h * DPH + dl0 + (lane >> 5);
            if (d < n) {
                float2 z; z.x = 0.f; z.y = 0.f;
                *(float2*)&out[(size_t)d * C_DIM + l31 * 2] = z;
            }
            continue;
        }

        const int myT   = half ? T1 : T0;
        const int myoff = half ? pre[dl0 + 1] : pre[dl0];
        const int d     = (b << SH) + h * DPH + dl0 + (half ? 1 : 0);
        const bool act  = (d < n);
        const float sd  = act ? s_dst[d] : 0.f;

        // slice 0: compute ee, then g -> write back into stag .y
        float ee0 = 0.f, bb0 = 0.f;
        int   sxa = 0;
        if (l31 < myT) {
            int2 r = stag[myoff + l31];
            sxa = r.x;
            bb0 = (float)(r.y & 0x7FFF) * ib;
            float z = s_src[sxa] + sd;
            ee0 = __expf(1.f / (1.f + __expf(-z)));
        }
        float ee1 = 0.f, bb1 = 0.f;
        int   sxb = 0;
        const bool two = (Tm > 32);
        if (two && l31 + 32 < myT) {
            int2 r = stag[myoff + 32 + l31];
            sxb = r.x;
            bb1 = (float)(r.y & 0x7FFF) * ib;
            float z = s_src[sxb] + sd;
            ee1 = __expf(1.f / (1.f + __expf(-z)));
        }

        float psl = ee0 + ee1;
        #pragma unroll
        for (int off = 16; off > 0; off >>= 1) psl += __shfl_xor(psl, off, 64);
        const float gl = lam / (psl + 1e-16f);
        if (l31 < myT)
            stag[myoff + l31].y = __float_as_int(fmaf(gl, ee0, oml * bb0));
        if (two && l31 + 32 < myT)
            stag[myoff + 32 + l31].y = __float_as_int(fmaf(gl, ee1, oml * bb1));
        // same wave wrote these slots -> wave-coherent, no sync needed

        float ax = 0.f, ay = 0.f;
        const int r0 = min(Tm, 32);
        int j = 0;
        for (; j + 8 <= r0; j += 8) {
            int sb[8]; float gb[8]; unsigned uu[8];
            #pragma unroll
            for (int k = 0; k < 8; ++k) {
                int2 rr = stag[myoff + j + k];          // LDS broadcast
                bool vld = (j + k < myT);
                sb[k] = vld ? rr.x : 0;
                gb[k] = vld ? __int_as_float(rr.y) : 0.f;
            }
            #pragma unroll
            for (int k = 0; k < 8; ++k)
                uu[k] = xp32[(size_t)sb[k] * 32 + l31];
            #pragma unroll
            for (int k = 0; k < 8; ++k) {
                ax = fmaf(__uint_as_float(uu[k] << 16),         gb[k], ax);
                ay = fmaf(__uint_as_float(uu[k] & 0xFFFF0000u), gb[k], ay);
            }
        }
        for (; j < r0; ++j) {
            int2 rr = stag[myoff + j];
            bool vld = (j < myT);
            int   sb = vld ? rr.x : 0;
            float gb = vld ? __int_as_float(rr.y) : 0.f;
            unsigned u = xp32[(size_t)sb * 32 + l31];
            ax = fmaf(__uint_as_float(u << 16),         gb, ax);
            ay = fmaf(__uint_as_float(u & 0xFFFF0000u), gb, ay);
        }
        if (two) {
            const int r1 = Tm - 32;
            for (int j2 = 0; j2 < r1; ++j2) {
                int2 rr = stag[myoff + 32 + j2];
                bool vld = (32 + j2 < myT);
                int   sb = vld ? rr.x : 0;
                float gb = vld ? __int_as_float(rr.y) : 0.f;
                unsigned u = xp32[(size_t)sb * 32 + l31];
                ax = fmaf(__uint_as_float(u << 16),         gb, ax);
                ay = fmaf(__uint_as_float(u & 0xFFFF0000u), gb, ay);
            }
        }

        if (act) {
            float2 v; v.x = ax; v.y = ay;
            *(float2*)&out[(size_t)d * C_DIM + l31 * 2] = v;
        }
    }
}

extern "C" void kernel_launch(void* const* d_in, const int* in_sizes, int n_in,
                              void* d_out, int out_size, void* d_ws, size_t ws_size,
                              hipStream_t stream)
{
    const float* x       = (const float*)d_in[0];
    const int*   ei      = (const int*)d_in[1];
    const float* beta    = (const float*)d_in[2];
    const float* lam01   = (const float*)d_in[3];
    const float* W       = (const float*)d_in[4];
    const float* att_src = (const float*)d_in[5];
    const float* att_dst = (const float*)d_in[6];
    float*       out     = (float*)d_out;

    const int n = in_sizes[0] / IN_DIM;   // 100000
    const int e = in_sizes[2];            // 1600000

    const int nbkt = (n + DP - 1) / DP;   // 196

    // workspace: gbuf 16.1MB + xp 12.8MB + s 0.8MB + gcur 1KB (~29.7MB)
    int2*           gbuf  = (int2*)d_ws;                               // nbkt*CAP
    unsigned short* xp_bf = (unsigned short*)(gbuf + (size_t)nbkt * CAP); // n*64
    float*          s_src = (float*)(xp_bf + (size_t)n * C_DIM);      // n
    float*          s_dst = s_src + n;                                 // n
    int*            gcur  = (int*)(s_dst + n);                         // NBKT2

    const int gd = (e + 2047) / 2048;       // bin chunks (8 edges/thread)
    const int gg = (n + 63) / 64;           // gemm chunks
    const int S  = (gd + gg + gd - 1) / gd; // bin every S-th block (~1:2)

    hipMemsetAsync(gcur, 0, NBKT2 * sizeof(int), stream);

    k_fused<<<gd + gg, 256, 0, stream>>>(x, W, att_src, att_dst, xp_bf,
                                         s_src, s_dst, ei, ei + e, beta,
                                         gcur, gbuf, n, e, gd, gg, S);
    k_sred<<<2 * nbkt, 512, 0, stream>>>(gcur, gbuf, xp_bf, s_src, s_dst,
                                         lam01, out, n);
}

// Round 13
// 182.847 us; speedup vs baseline: 1.0817x; 1.0817x over previous
//
#include <hip/hip_runtime.h>
#include <hip/hip_bf16.h>
#include <hip/hip_fp16.h>

#define IN_DIM 128
#define C_DIM 64
#define SH    9            // dsts per bucket = 512
#define DP    512
#define CAP   10240        // records per bucket region (avg 8192, +22 sigma)
#define NBKT2 256          // padded bucket-array size in K1 (196 actual)
#define STG   8192         // LDS-staged records in k_sort (mean m = 8192)

typedef __attribute__((ext_vector_type(8))) short bf16x8;
typedef __attribute__((ext_vector_type(4))) float f32x4;

__device__ __forceinline__ short f2b(float f) {
    unsigned u = __float_as_uint(f);
    unsigned r = (u + 0x7FFFu + ((u >> 16) & 1u)) >> 16;   // RNE to bf16
    return (short)r;
}

// record: x = src; y = (d_local<<15) | beta15   (9+15 = 24 bits used)
__device__ __forceinline__ int2 make_rec(int s, int dl, float b) {
    unsigned b15 = (unsigned)(b * 32767.f + 0.5f) & 0x7FFFu;
    return make_int2(s, (int)(((unsigned)dl << 15) | b15));
}

// ---------------------------------------------------------------------------
// K1 fused (UNCHANGED from round 11): gemm role + LDS-binned edge staging.
// ---------------------------------------------------------------------------
__global__ __launch_bounds__(256) void k_fused(
    const float* __restrict__ x,
    const float* __restrict__ W,
    const float* __restrict__ att_src,
    const float* __restrict__ att_dst,
    unsigned short* __restrict__ xp_bf,
    float* __restrict__ s_src,
    float* __restrict__ s_dst,
    const int* __restrict__ ei_src,
    const int* __restrict__ ei_dst,
    const float* __restrict__ beta,
    int* __restrict__ gcur,
    int2* __restrict__ gbuf,
    int n, int e, int gd, int gg, int S)
{
    __shared__ char smem[23552];

    const int bid = (int)blockIdx.x;
    const int q   = bid / S;
    const bool bin_role = (bid % S == 0) && (q < gd);
    const int chunk = bin_role ? q : (bid - min(gd, q + 1));
    const int t = threadIdx.x;

    if (bin_role) {
        int2*           stag  = (int2*)smem;                     // 2048 recs
        unsigned short* sbkt  = (unsigned short*)(smem + 16384); // 2048
        int*            bcnt  = (int*)(smem + 20480);            // 256
        int*            bpre  = (int*)(smem + 21504);            // 256
        int*            gbase = (int*)(smem + 22528);            // 256

        for (int i = t; i < NBKT2; i += 256) bcnt[i] = 0;
        __syncthreads();

        const int i0 = (chunk * 256 + t) * 8;
        int   sv[8], dv[8], bkt[8], lr[8];
        float bv[8];
        int   nk = 0;
        if (i0 + 7 < e) {
            int4   sa = *(const int4*)&ei_src[i0];
            int4   sb = *(const int4*)&ei_src[i0 + 4];
            int4   da = *(const int4*)&ei_dst[i0];
            int4   db = *(const int4*)&ei_dst[i0 + 4];
            float4 ba = *(const float4*)&beta[i0];
            float4 bb = *(const float4*)&beta[i0 + 4];
            sv[0]=sa.x; sv[1]=sa.y; sv[2]=sa.z; sv[3]=sa.w;
            sv[4]=sb.x; sv[5]=sb.y; sv[6]=sb.z; sv[7]=sb.w;
            dv[0]=da.x; dv[1]=da.y; dv[2]=da.z; dv[3]=da.w;
            dv[4]=db.x; dv[5]=db.y; dv[6]=db.z; dv[7]=db.w;
            bv[0]=ba.x; bv[1]=ba.y; bv[2]=ba.z; bv[3]=ba.w;
            bv[4]=bb.x; bv[5]=bb.y; bv[6]=bb.z; bv[7]=bb.w;
            nk = 8;
        } else {
            for (int k = 0; i0 + k < e && k < 8; ++k) {
                sv[k] = ei_src[i0 + k];
                dv[k] = ei_dst[i0 + k];
                bv[k] = beta[i0 + k];
                ++nk;
            }
        }
        for (int k = 0; k < nk; ++k) {
            bkt[k] = dv[k] >> SH;
            lr[k]  = atomicAdd(&bcnt[bkt[k]], 1);
        }
        __syncthreads();

        if (t < 64) {                        // scan 256 entries, 4/lane
            int c[4], s = 0;
            #pragma unroll
            for (int j = 0; j < 4; ++j) { c[j] = bcnt[4 * t + j]; s += c[j]; }
            int v = s;
            #pragma unroll
            for (int off = 1; off < 64; off <<= 1) {
                int u = __shfl_up(v, off, 64);
                if (t >= off) v += u;
            }
            int base = v - s;
            #pragma unroll
            for (int j = 0; j < 4; ++j) { bpre[4 * t + j] = base; base += c[j]; }
        }
        __syncthreads();

        if (t < NBKT2) {
            int c = bcnt[t];
            if (c > 0) gbase[t] = atomicAdd(&gcur[t], c);
        }
        __syncthreads();

        for (int k = 0; k < nk; ++k) {
            int slot = bpre[bkt[k]] + lr[k];
            stag[slot] = make_rec(sv[k], dv[k] & (DP - 1), bv[k]);
            sbkt[slot] = (unsigned short)bkt[k];
        }
        __syncthreads();

        const int total = bpre[NBKT2 - 1] + bcnt[NBKT2 - 1];
        for (int i = t; i < total; i += 256) {
            int bb = sbkt[i];
            int al = gbase[bb] + (i - bpre[bb]);
            if (al < CAP) gbuf[(size_t)bb * CAP + al] = stag[i];
        }
        return;
    }

    // ---- GEMM role (unchanged) ----
    short (*WT)[136] = (short(*)[136])smem;
    for (int i = t; i < IN_DIM * C_DIM; i += 256) {
        int k = i >> 6, nn = i & 63;
        WT[nn][k] = f2b(W[i]);
    }
    __syncthreads();

    const int lane = t & 63;
    const int wv   = t >> 6;
    const int base = (chunk * 4 + wv) * 16;
    if (base >= n) return;

    const int m    = lane & 15;
    const int quad = lane >> 4;
    int rowA = base + m;
    if (rowA >= n) rowA = n - 1;
    const float* xr = x + (size_t)rowA * IN_DIM + quad * 8;

    f32x4 acc[4] = {{0,0,0,0},{0,0,0,0},{0,0,0,0},{0,0,0,0}};

    #pragma unroll
    for (int ks = 0; ks < 4; ++ks) {
        float4 f0 = *(const float4*)(xr + ks * 32);
        float4 f1 = *(const float4*)(xr + ks * 32 + 4);
        bf16x8 a;
        a[0] = f2b(f0.x); a[1] = f2b(f0.y); a[2] = f2b(f0.z); a[3] = f2b(f0.w);
        a[4] = f2b(f1.x); a[5] = f2b(f1.y); a[6] = f2b(f1.z); a[7] = f2b(f1.w);
        #pragma unroll
        for (int nt = 0; nt < 4; ++nt) {
            bf16x8 bb = *(const bf16x8*)&WT[nt * 16 + m][ks * 32 + quad * 8];
            acc[nt] = __builtin_amdgcn_mfma_f32_16x16x32_bf16(a, bb, acc[nt], 0, 0, 0);
        }
    }

    float asv[4], adv[4];
    #pragma unroll
    for (int nt = 0; nt < 4; ++nt) {
        asv[nt] = att_src[nt * 16 + m];
        adv[nt] = att_dst[nt * 16 + m];
    }
    #pragma unroll
    for (int qq = 0; qq < 4; ++qq) {
        float vs = 0.f, vd = 0.f;
        #pragma unroll
        for (int nt = 0; nt < 4; ++nt) {
            vs = fmaf(acc[nt][qq], asv[nt], vs);
            vd = fmaf(acc[nt][qq], adv[nt], vd);
        }
        #pragma unroll
        for (int off = 8; off > 0; off >>= 1) {
            vs += __shfl_xor(vs, off, 64);
            vd += __shfl_xor(vd, off, 64);
        }
        int r = base + quad * 4 + qq;
        if (m == 0 && r < n) { s_src[r] = vs; s_dst[r] = vd; }
    }

    #pragma unroll
    for (int nt = 0; nt < 4; ++nt)
        #pragma unroll
        for (int qq = 0; qq < 4; ++qq) {
            int r = base + quad * 4 + qq;
            if (r < n)
                xp_bf[(size_t)r * C_DIM + nt * 16 + m] = (unsigned short)f2b(acc[nt][qq]);
        }
}

// ---------------------------------------------------------------------------
// K2: per-bucket dst-sort (1024 threads, r11). NEW: records staged in LDS
// during the count pass so the scatter pass reads LDS instead of re-reading
// gbuf (tail >STG rare, read from L2-hot gbuf). 72KB LDS -> 2 blocks/CU.
// ---------------------------------------------------------------------------
__global__ __launch_bounds__(1024) void k_sort(
    const int* __restrict__ gcur,
    const int2* __restrict__ gbuf,
    int2* __restrict__ gsort,
    int2* __restrict__ gmeta,
    int n)
{
    __shared__ int2 stag[STG];
    __shared__ int cnt2[DP];
    __shared__ int pre[DP + 1];
    __shared__ int fill[DP];

    const int b = (int)blockIdx.x;
    const int t = threadIdx.x;
    const int m = min(gcur[b], CAP);

    for (int i = t; i < DP; i += 1024) { cnt2[i] = 0; fill[i] = 0; }
    __syncthreads();

    for (int i = t; i < m; i += 1024) {
        int2 r = gbuf[(size_t)b * CAP + i];
        if (i < STG) stag[i] = r;
        atomicAdd(&cnt2[(r.y >> 15) & (DP - 1)], 1);
    }
    __syncthreads();

    if (t < 64) {                            // scan 512 entries, 8/lane
        int c[8], s = 0;
        #pragma unroll
        for (int j = 0; j < 8; ++j) { c[j] = cnt2[8 * t + j]; s += c[j]; }
        int v = s;
        #pragma unroll
        for (int off = 1; off < 64; off <<= 1) {
            int u = __shfl_up(v, off, 64);
            if (t >= off) v += u;
        }
        int base = v - s;
        #pragma unroll
        for (int j = 0; j < 8; ++j) { pre[8 * t + j] = base; base += c[j]; }
        if (t == 63) pre[DP] = v;
    }
    __syncthreads();

    for (int i = t; i < DP; i += 1024) {
        int d = (b << SH) + i;
        if (d < n) gmeta[d] = make_int2(b * CAP + pre[i], pre[i + 1] - pre[i]);
    }
    for (int i = t; i < m; i += 1024) {
        int2 r = (i < STG) ? stag[i] : gbuf[(size_t)b * CAP + i];
        int dl = (r.y >> 15) & (DP - 1);
        int l  = atomicAdd(&fill[dl], 1);
        gsort[(size_t)b * CAP + pre[dl] + l] = r;
    }
}

// ---------------------------------------------------------------------------
// K3: half-wave-per-dst segmented reduction (r11 body). NEW: XCD-affinity
// blockIdx swizzle -- bucket b's gsort region was written by k_sort block b
// on XCD b%8 (round-robin); map each k_seg block so bid%8 == b%8, making
// gsort reads local-L2 hits. Coverage: grid = 8*mmax*64; blocks with
// b >= nbkt or d0 >= n no-op. Correct for ANY actual block->XCD mapping.
// ---------------------------------------------------------------------------
__global__ __launch_bounds__(256) void k_seg(
    const int2* __restrict__ gsort,
    const int2* __restrict__ gmeta,
    const unsigned short* __restrict__ xp_bf,
    const float* __restrict__ s_src,
    const float* __restrict__ s_dst,
    const float* __restrict__ lam01,
    float* __restrict__ out,
    int n, int nbkt)
{
    const int bid  = (int)blockIdx.x;
    const int xcd  = bid & 7;
    const int jj   = bid >> 3;
    const int b    = xcd + 8 * (jj >> 6);     // bucket this block serves
    if (b >= nbkt) return;
    const int bs   = b * 64 + (jj & 63);      // logical block index (r11's blockIdx)

    const int lane = threadIdx.x & 63;
    const int wv   = threadIdx.x >> 6;
    const int d0   = bs * 8 + wv * 2;
    if (d0 >= n) return;
    const int d1   = d0 + 1;
    const bool has1 = (d1 < n);

    const int4 mt = *(const int4*)&gmeta[d0];   // {off0,T0,off1,T1}
    const int T0 = min(mt.y, 64);
    const int T1 = has1 ? min(mt.w, 64) : 0;
    const int Tm = max(T0, T1);

    const int half = lane & 32;
    const int l31  = lane & 31;
    const int myT   = half ? T1 : T0;
    const int myoff = half ? mt.z : mt.x;
    const int myd   = half ? (has1 ? d1 : d0) : d0;

    const float sd  = s_dst[myd];
    const float lam = lam01[0];
    const float oml = 1.f - lam;
    const float ib  = 1.f / 32767.f;

    int sx0 = 0; float ee0 = 0.f, bb0 = 0.f;
    if (l31 < myT) {
        int2 r = gsort[(size_t)myoff + l31];
        sx0 = r.x;
        bb0 = (float)(r.y & 0x7FFF) * ib;
        float z = s_src[sx0] + sd;
        ee0 = __expf(1.f / (1.f + __expf(-z)));
    }
    int sx1 = 0; float ee1 = 0.f, bb1 = 0.f;
    const bool two = (Tm > 32);
    if (two && l31 + 32 < myT) {
        int2 r = gsort[(size_t)myoff + l31 + 32];
        sx1 = r.x;
        bb1 = (float)(r.y & 0x7FFF) * ib;
        float z = s_src[sx1] + sd;
        ee1 = __expf(1.f / (1.f + __expf(-z)));
    }

    float psl = ee0 + ee1;
    #pragma unroll
    for (int off = 16; off > 0; off >>= 1) psl += __shfl_xor(psl, off, 64);
    const float gl = lam / (psl + 1e-16f);
    const float g0 = fmaf(gl, ee0, oml * bb0);
    const float g1 = fmaf(gl, ee1, oml * bb1);

    const unsigned* xp32 = (const unsigned*)xp_bf;
    float ax = 0.f, ay = 0.f;

    const int r0 = min(Tm, 32);
    int j = 0;
    for (; j + 8 <= r0; j += 8) {
        int sb[8]; float gb[8]; unsigned uu[8];
        #pragma unroll
        for (int k = 0; k < 8; ++k) {
            sb[k] = __shfl(sx0, half + j + k, 64);
            gb[k] = __shfl(g0,  half + j + k, 64);
        }
        #pragma unroll
        for (int k = 0; k < 8; ++k)
            uu[k] = xp32[(size_t)sb[k] * 32 + l31];
        #pragma unroll
        for (int k = 0; k < 8; ++k) {
            ax = fmaf(__uint_as_float(uu[k] << 16),         gb[k], ax);
            ay = fmaf(__uint_as_float(uu[k] & 0xFFFF0000u), gb[k], ay);
        }
    }
    for (; j + 4 <= r0; j += 4) {
        int sb[4]; float gb[4]; unsigned uu[4];
        #pragma unroll
        for (int k = 0; k < 4; ++k) {
            sb[k] = __shfl(sx0, half + j + k, 64);
            gb[k] = __shfl(g0,  half + j + k, 64);
        }
        #pragma unroll
        for (int k = 0; k < 4; ++k)
            uu[k] = xp32[(size_t)sb[k] * 32 + l31];
        #pragma unroll
        for (int k = 0; k < 4; ++k) {
            ax = fmaf(__uint_as_float(uu[k] << 16),         gb[k], ax);
            ay = fmaf(__uint_as_float(uu[k] & 0xFFFF0000u), gb[k], ay);
        }
    }
    for (; j < r0; ++j) {
        int sb = __shfl(sx0, half + j, 64);
        float gb = __shfl(g0, half + j, 64);
        unsigned u = xp32[(size_t)sb * 32 + l31];
        ax = fmaf(__uint_as_float(u << 16),         gb, ax);
        ay = fmaf(__uint_as_float(u & 0xFFFF0000u), gb, ay);
    }
    if (two) {
        const int r1 = Tm - 32;
        for (int j2 = 0; j2 < r1; ++j2) {
            int sb = __shfl(sx1, half + j2, 64);
            float gb = __shfl(g1, half + j2, 64);
            unsigned u = xp32[(size_t)sb * 32 + l31];
            ax = fmaf(__uint_as_float(u << 16),         gb, ax);
            ay = fmaf(__uint_as_float(u & 0xFFFF0000u), gb, ay);
        }
    }

    const int row = d0 + (lane >> 5);
    if (row < n) {
        float2 v; v.x = ax; v.y = ay;
        *(float2*)&out[(size_t)row * C_DIM + l31 * 2] = v;
    }
}

extern "C" void kernel_launch(void* const* d_in, const int* in_sizes, int n_in,
                              void* d_out, int out_size, void* d_ws, size_t ws_size,
                              hipStream_t stream)
{
    const float* x       = (const float*)d_in[0];
    const int*   ei      = (const int*)d_in[1];
    const float* beta    = (const float*)d_in[2];
    const float* lam01   = (const float*)d_in[3];
    const float* W       = (const float*)d_in[4];
    const float* att_src = (const float*)d_in[5];
    const float* att_dst = (const float*)d_in[6];
    float*       out     = (float*)d_out;

    const int n = in_sizes[0] / IN_DIM;   // 100000
    const int e = in_sizes[2];            // 1600000

    const int nbkt = (n + DP - 1) / DP;   // 196

    // workspace: gbuf 16.1MB + gsort 16.1MB + xp 12.8MB + s 0.8MB
    //          + gmeta 0.8MB + gcur 1KB  (~46.6MB)
    int2*           gbuf  = (int2*)d_ws;                               // nbkt*CAP
    int2*           gsort = gbuf + (size_t)nbkt * CAP;                 // nbkt*CAP
    unsigned short* xp_bf = (unsigned short*)(gsort + (size_t)nbkt * CAP); // n*64
    float*          s_src = (float*)(xp_bf + (size_t)n * C_DIM);      // n
    float*          s_dst = s_src + n;                                 // n
    int2*           gmeta = (int2*)(s_dst + n);                        // n+2
    int*            gcur  = (int*)(gmeta + n + 2);                     // NBKT2

    const int gd = (e + 2047) / 2048;       // bin chunks (8 edges/thread)
    const int gg = (n + 63) / 64;           // gemm chunks
    const int S  = (gd + gg + gd - 1) / gd; // bin every S-th block (~1:2)

    const int mmax   = (nbkt + 7) / 8;      // 25
    const int segGrid = 8 * mmax * 64;      // 12800 (swizzled coverage)

    hipMemsetAsync(gcur, 0, NBKT2 * sizeof(int), stream);

    k_fused<<<gd + gg, 256, 0, stream>>>(x, W, att_src, att_dst, xp_bf,
                                         s_src, s_dst, ei, ei + e, beta,
                                         gcur, gbuf, n, e, gd, gg, S);
    k_sort<<<nbkt, 1024, 0, stream>>>(gcur, gbuf, gsort, gmeta, n);
    k_seg <<<segGrid, 256, 0, stream>>>(gsort, gmeta, xp_bf, s_src, s_dst,
                                        lam01, out, n, nbkt);
}